// Round 2
// baseline (330.704 us; speedup 1.0000x reference)
//
#include <hip/hip_runtime.h>

#define NN 4
#define KK 8
#define HH 512
#define WW 512
#define CC 16
#define PP 1000000

// ---------------------------------------------------------------------------
// Kernel 1: transpose ptclds (C=16, P=1e6) -> (P, C) so that a gather at
// index p reads ONE contiguous 64B cache line instead of 16 lines 4MB apart.
// Reads: for each c, consecutive lanes read consecutive p -> coalesced.
// Writes: each lane writes 64B contiguous at p*16 floats -> consecutive lanes
// write consecutive 64B chunks -> fully coalesced dwordx4 stores.
// ---------------------------------------------------------------------------
__global__ __launch_bounds__(256) void transpose_tbl(
    const float* __restrict__ ptclds, float* __restrict__ tbl) {
  int p = blockIdx.x * blockDim.x + threadIdx.x;
  if (p >= PP) return;
  float v[CC];
#pragma unroll
  for (int c = 0; c < CC; ++c) v[c] = ptclds[(size_t)c * PP + p];
  float4* o = reinterpret_cast<float4*>(tbl + (size_t)p * CC);
  o[0] = make_float4(v[0], v[1], v[2], v[3]);
  o[1] = make_float4(v[4], v[5], v[6], v[7]);
  o[2] = make_float4(v[8], v[9], v[10], v[11]);
  o[3] = make_float4(v[12], v[13], v[14], v[15]);
}

// ---------------------------------------------------------------------------
// Kernel 2: one thread per (n,h,w) pixel.
//   softmax over k of 1/(z+1e-6), z = (zbuf<0 ? -1e-4 : zbuf)
//   out[n][c][hw] = sum_k w_k * tbl[idx_k][c]
// TRANSPOSED=1: gather 4x float4 per index (64B line). =0: strided fallback.
// ---------------------------------------------------------------------------
template <int TRANSPOSED>
__global__ __launch_bounds__(256) void composite(
    const int* __restrict__ frag, const float* __restrict__ zbuf,
    const float* __restrict__ tbl, float* __restrict__ out) {
  const int HW = HH * WW;
  int g = blockIdx.x * blockDim.x + threadIdx.x;
  if (g >= NN * HW) return;
  int n = g / HW;
  int hw = g - n * HW;

  const int* fp = frag + (size_t)n * KK * HW + hw;
  const float* zp = zbuf + (size_t)n * KK * HW + hw;

  float imp[KK];
  int idx[KK];
  float m = -3.402823e38f;
#pragma unroll
  for (int k = 0; k < KK; ++k) {
    float z = zp[(size_t)k * HW];
    idx[k] = fp[(size_t)k * HW];
    z = (z < 0.0f) ? -0.0001f : z;
    float im = 1.0f / (z + 1e-6f);
    imp[k] = im;
    m = fmaxf(m, im);
  }
  float e[KK];
  float s = 0.0f;
#pragma unroll
  for (int k = 0; k < KK; ++k) {
    e[k] = __expf(imp[k] - m);
    s += e[k];
  }
  float rs = 1.0f / s;

  float acc[CC];
#pragma unroll
  for (int c = 0; c < CC; ++c) acc[c] = 0.0f;

#pragma unroll
  for (int k = 0; k < KK; ++k) {
    float wk = e[k] * rs;
    if (TRANSPOSED) {
      const float4* tp = reinterpret_cast<const float4*>(tbl + (size_t)idx[k] * CC);
      float4 a = tp[0], b = tp[1], c4 = tp[2], d = tp[3];
      acc[0]  += wk * a.x;  acc[1]  += wk * a.y;
      acc[2]  += wk * a.z;  acc[3]  += wk * a.w;
      acc[4]  += wk * b.x;  acc[5]  += wk * b.y;
      acc[6]  += wk * b.z;  acc[7]  += wk * b.w;
      acc[8]  += wk * c4.x; acc[9]  += wk * c4.y;
      acc[10] += wk * c4.z; acc[11] += wk * c4.w;
      acc[12] += wk * d.x;  acc[13] += wk * d.y;
      acc[14] += wk * d.z;  acc[15] += wk * d.w;
    } else {
#pragma unroll
      for (int c = 0; c < CC; ++c)
        acc[c] += wk * tbl[(size_t)c * PP + idx[k]];
    }
  }

  float* op = out + (size_t)n * CC * HW + hw;
#pragma unroll
  for (int c = 0; c < CC; ++c) op[(size_t)c * HW] = acc[c];
}

extern "C" void kernel_launch(void* const* d_in, const int* in_sizes, int n_in,
                              void* d_out, int out_size, void* d_ws, size_t ws_size,
                              hipStream_t stream) {
  const int* frag = (const int*)d_in[0];
  const float* zbuf = (const float*)d_in[1];
  const float* ptclds = (const float*)d_in[2];
  float* out = (float*)d_out;

  const int HW = HH * WW;
  const int npix = NN * HW;  // 1,048,576
  const size_t tbl_bytes = (size_t)PP * CC * sizeof(float);  // 64 MB

  if (ws_size >= tbl_bytes) {
    float* tbl = (float*)d_ws;
    transpose_tbl<<<(PP + 255) / 256, 256, 0, stream>>>(ptclds, tbl);
    composite<1><<<(npix + 255) / 256, 256, 0, stream>>>(frag, zbuf, tbl, out);
  } else {
    composite<0><<<(npix + 255) / 256, 256, 0, stream>>>(frag, zbuf, ptclds, out);
  }
}

// Round 3
// 322.382 us; speedup vs baseline: 1.0258x; 1.0258x over previous
//
#include <hip/hip_runtime.h>

#define NN 4
#define KK 8
#define HH 512
#define WW 512
#define CC 16
#define PP 1000000

// ---------------------------------------------------------------------------
// Kernel 1: LDS-staged transpose ptclds (C=16, P=1e6) -> (P, C).
// Reads:  per wave, 64 consecutive p for one channel -> 256B coalesced.
// Writes: lanes remapped (po = tid/4, q = tid%4) so the block's float4
//         stores cover a contiguous 4KB span -> fully coalesced dwordx4.
// ---------------------------------------------------------------------------
__global__ __launch_bounds__(256) void transpose_tbl(
    const float* __restrict__ ptclds, float* __restrict__ tbl) {
  __shared__ float lds[64][17];            // +1 pad: conflict-free staging
  const int base = blockIdx.x * 64;        // 64 points per block
  const int p  = threadIdx.x & 63;
  const int c0 = (threadIdx.x >> 6) * 4;   // wave w handles channels 4w..4w+3
#pragma unroll
  for (int i = 0; i < 4; ++i) {
    int c = c0 + i;
    lds[p][c] = ptclds[(size_t)c * PP + base + p];
  }
  __syncthreads();
  const int po = threadIdx.x >> 2;         // point within tile
  const int q  = threadIdx.x & 3;          // which float4 of the 16 channels
  float4 v = make_float4(lds[po][q * 4 + 0], lds[po][q * 4 + 1],
                         lds[po][q * 4 + 2], lds[po][q * 4 + 3]);
  reinterpret_cast<float4*>(tbl)[(size_t)blockIdx.x * 256 + threadIdx.x] = v;
}

// ---------------------------------------------------------------------------
// Kernel 2: one thread per (n,h,w) pixel.
//   softmax over k of 1/(z+1e-6), z = (zbuf<0 ? -1e-4 : zbuf)
//   out[n][c][hw] = (sum_k e_k * tbl[idx_k][c]) / sum_k e_k
// Gathers batched 4 indices (16x float4) at a time for memory-level
// parallelism — round-2 profile showed VGPR=36 / VALUBusy 5.8%: the
// compiler had serialized the gather loads (latency-bound).
// ---------------------------------------------------------------------------
template <int TRANSPOSED>
__global__ __launch_bounds__(256) void composite(
    const int* __restrict__ frag, const float* __restrict__ zbuf,
    const float* __restrict__ tbl, float* __restrict__ out) {
  const int HW = HH * WW;                  // 262144 = 2^18
  int g = blockIdx.x * blockDim.x + threadIdx.x;
  if (g >= NN * HW) return;
  int n = g >> 18;
  int hw = g & (HW - 1);

  const int* fp = frag + (size_t)n * KK * HW + hw;
  const float* zp = zbuf + (size_t)n * KK * HW + hw;

  int idx[KK];
  float e[KK];
  float m = -3.402823e38f;
#pragma unroll
  for (int k = 0; k < KK; ++k) {
    float z = zp[k * HW];
    idx[k] = fp[k * HW];
    z = (z < 0.0f) ? -0.0001f : z;
    float im = 1.0f / (z + 1e-6f);
    e[k] = im;
    m = fmaxf(m, im);
  }
  float s = 0.0f;
#pragma unroll
  for (int k = 0; k < KK; ++k) {
    e[k] = __expf(e[k] - m);
    s += e[k];
  }
  float rs = 1.0f / s;

  float acc[CC];
#pragma unroll
  for (int c = 0; c < CC; ++c) acc[c] = 0.0f;

  if (TRANSPOSED) {
#pragma unroll
    for (int kb = 0; kb < 2; ++kb) {
      // ---- load phase: 16 independent dwordx4 loads in flight ----
      float4 q0[4], q1[4], q2[4], q3[4];
#pragma unroll
      for (int j = 0; j < 4; ++j) {
        const float4* tp =
            reinterpret_cast<const float4*>(tbl + (size_t)idx[kb * 4 + j] * CC);
        q0[j] = tp[0]; q1[j] = tp[1]; q2[j] = tp[2]; q3[j] = tp[3];
      }
      // ---- FMA phase ----
#pragma unroll
      for (int j = 0; j < 4; ++j) {
        float wk = e[kb * 4 + j];
        acc[0]  += wk * q0[j].x;  acc[1]  += wk * q0[j].y;
        acc[2]  += wk * q0[j].z;  acc[3]  += wk * q0[j].w;
        acc[4]  += wk * q1[j].x;  acc[5]  += wk * q1[j].y;
        acc[6]  += wk * q1[j].z;  acc[7]  += wk * q1[j].w;
        acc[8]  += wk * q2[j].x;  acc[9]  += wk * q2[j].y;
        acc[10] += wk * q2[j].z;  acc[11] += wk * q2[j].w;
        acc[12] += wk * q3[j].x;  acc[13] += wk * q3[j].y;
        acc[14] += wk * q3[j].z;  acc[15] += wk * q3[j].w;
      }
    }
  } else {
#pragma unroll
    for (int k = 0; k < KK; ++k) {
#pragma unroll
      for (int c = 0; c < CC; ++c)
        acc[c] += e[k] * tbl[(size_t)c * PP + idx[k]];
    }
  }

  float* op = out + (size_t)n * CC * HW + hw;
#pragma unroll
  for (int c = 0; c < CC; ++c) op[c * HW] = acc[c] * rs;
}

extern "C" void kernel_launch(void* const* d_in, const int* in_sizes, int n_in,
                              void* d_out, int out_size, void* d_ws, size_t ws_size,
                              hipStream_t stream) {
  const int* frag = (const int*)d_in[0];
  const float* zbuf = (const float*)d_in[1];
  const float* ptclds = (const float*)d_in[2];
  float* out = (float*)d_out;

  const int HW = HH * WW;
  const int npix = NN * HW;  // 1,048,576
  const size_t tbl_bytes = (size_t)PP * CC * sizeof(float);  // 64 MB

  if (ws_size >= tbl_bytes) {
    float* tbl = (float*)d_ws;
    transpose_tbl<<<PP / 64, 256, 0, stream>>>(ptclds, tbl);
    composite<1><<<(npix + 255) / 256, 256, 0, stream>>>(frag, zbuf, tbl, out);
  } else {
    composite<0><<<(npix + 255) / 256, 256, 0, stream>>>(frag, zbuf, ptclds, out);
  }
}

// Round 8
// 308.011 us; speedup vs baseline: 1.0737x; 1.0467x over previous
//
#include <hip/hip_runtime.h>

#define NN 4
#define KK 8
#define HH 512
#define WW 512
#define CC 16
#define PP 1000000
#define HWPIX (HH * WW)  // 262144 = 2^18

typedef float f32x4 __attribute__((ext_vector_type(4)));

// ---------------------------------------------------------------------------
// Kernel 1: transpose ptclds (C=16, P=1e6) -> (P, C). 256 points per block.
// Load phase: thread (c = tid>>4, t = tid&15), 4x float4 at p = r*64 + t*4
//   -> each wave instr: 16 lanes x 16B contiguous per channel group = 256B.
// LDS [256][17]: pad 17 makes both write (p*17+c) and read patterns 2-way
//   bank aliasing only (free on CDNA4).
// Store phase: thread (po = tid>>2 + 64w, q = tid&3) writes float4 #q of
//   point po -> each wave instr covers a contiguous 1KB span. Fully coalesced.
// ---------------------------------------------------------------------------
__global__ __launch_bounds__(256) void transpose_tbl(
    const float* __restrict__ ptclds, float* __restrict__ tbl) {
  __shared__ float lds[256][17];
  const int base = blockIdx.x * 256;
  const int c = threadIdx.x >> 4;
  const int t = threadIdx.x & 15;
#pragma unroll
  for (int r = 0; r < 4; ++r) {
    int p = r * 64 + t * 4;
    int pg = base + p;
    if (pg < PP) {
      f32x4 v = __builtin_nontemporal_load(
          reinterpret_cast<const f32x4*>(ptclds + (size_t)c * PP + pg));
      lds[p + 0][c] = v.x;
      lds[p + 1][c] = v.y;
      lds[p + 2][c] = v.z;
      lds[p + 3][c] = v.w;
    }
  }
  __syncthreads();
  const int q = threadIdx.x & 3;
#pragma unroll
  for (int w = 0; w < 4; ++w) {
    int po = (threadIdx.x >> 2) + 64 * w;
    int pg = base + po;
    if (pg < PP) {
      f32x4 v;
      v.x = lds[po][q * 4 + 0];
      v.y = lds[po][q * 4 + 1];
      v.z = lds[po][q * 4 + 2];
      v.w = lds[po][q * 4 + 3];
      reinterpret_cast<f32x4*>(tbl)[(size_t)pg * 4 + q] = v;
    }
  }
}

// ---------------------------------------------------------------------------
// Kernel 2: one thread per (n,h,w) pixel.
// Round-3 post-mortem: VGPR=40 proved the compiler serialized the gathers
// (latency-bound, ~2.5 lines in flight/wave). This version:
//   - __launch_bounds__(256, 2): VGPR budget up to ~256 so 32 gather results
//     can be held in registers.
//   - issue ALL 32 dwordx4 gather loads, do softmax VALU while they fly,
//     then sched_barrier(0) so the scheduler cannot sink loads past it.
// ---------------------------------------------------------------------------
template <int TRANSPOSED>
__global__ __launch_bounds__(256, 2) void composite(
    const int* __restrict__ frag, const float* __restrict__ zbuf,
    const float* __restrict__ tbl, float* __restrict__ out) {
  int g = blockIdx.x * 256 + threadIdx.x;
  int n = g >> 18;
  int hw = g & (HWPIX - 1);

  const int* fp = frag + (size_t)n * KK * HWPIX + hw;
  const float* zp = zbuf + (size_t)n * KK * HWPIX + hw;

  int idx[KK];
#pragma unroll
  for (int k = 0; k < KK; ++k)
    idx[k] = __builtin_nontemporal_load(fp + k * HWPIX);
  float zv[KK];
#pragma unroll
  for (int k = 0; k < KK; ++k)
    zv[k] = __builtin_nontemporal_load(zp + k * HWPIX);

  float acc[CC];
  float s;

  if (TRANSPOSED) {
    // ---- issue all 32 gather loads (8 indices x 4 float4 = full 64B line)
    f32x4 q[KK][4];
#pragma unroll
    for (int k = 0; k < KK; ++k) {
      const f32x4* tp = reinterpret_cast<const f32x4*>(tbl) + (size_t)idx[k] * 4;
      q[k][0] = tp[0];
      q[k][1] = tp[1];
      q[k][2] = tp[2];
      q[k][3] = tp[3];
    }
    // ---- softmax weights while the gathers are in flight
    float e[KK];
    float m = -3.402823e38f;
#pragma unroll
    for (int k = 0; k < KK; ++k) {
      float z = zv[k];
      z = (z < 0.0f) ? -0.0001f : z;
      float im = 1.0f / (z + 1e-6f);
      e[k] = im;
      m = fmaxf(m, im);
    }
    s = 0.0f;
#pragma unroll
    for (int k = 0; k < KK; ++k) {
      e[k] = __expf(e[k] - m);
      s += e[k];
    }
    // ---- nothing may cross: all loads are issued before any FMA
    __builtin_amdgcn_sched_barrier(0);
#pragma unroll
    for (int k = 0; k < KK; ++k) {
      float wk = e[k];
#pragma unroll
      for (int c4 = 0; c4 < 4; ++c4) {
        if (k == 0) {
          acc[c4 * 4 + 0] = wk * q[k][c4].x;
          acc[c4 * 4 + 1] = wk * q[k][c4].y;
          acc[c4 * 4 + 2] = wk * q[k][c4].z;
          acc[c4 * 4 + 3] = wk * q[k][c4].w;
        } else {
          acc[c4 * 4 + 0] += wk * q[k][c4].x;
          acc[c4 * 4 + 1] += wk * q[k][c4].y;
          acc[c4 * 4 + 2] += wk * q[k][c4].z;
          acc[c4 * 4 + 3] += wk * q[k][c4].w;
        }
      }
    }
  } else {
    float e[KK];
    float m = -3.402823e38f;
#pragma unroll
    for (int k = 0; k < KK; ++k) {
      float z = zv[k];
      z = (z < 0.0f) ? -0.0001f : z;
      float im = 1.0f / (z + 1e-6f);
      e[k] = im;
      m = fmaxf(m, im);
    }
    s = 0.0f;
#pragma unroll
    for (int k = 0; k < KK; ++k) {
      e[k] = __expf(e[k] - m);
      s += e[k];
    }
#pragma unroll
    for (int c = 0; c < CC; ++c) acc[c] = 0.0f;
#pragma unroll
    for (int k = 0; k < KK; ++k)
#pragma unroll
      for (int c = 0; c < CC; ++c)
        acc[c] += e[k] * tbl[(size_t)c * PP + idx[k]];
  }

  float rs = 1.0f / s;
  float* op = out + (size_t)n * CC * HWPIX + hw;
#pragma unroll
  for (int c = 0; c < CC; ++c)
    __builtin_nontemporal_store(acc[c] * rs, op + c * HWPIX);
}

extern "C" void kernel_launch(void* const* d_in, const int* in_sizes, int n_in,
                              void* d_out, int out_size, void* d_ws, size_t ws_size,
                              hipStream_t stream) {
  const int* frag = (const int*)d_in[0];
  const float* zbuf = (const float*)d_in[1];
  const float* ptclds = (const float*)d_in[2];
  float* out = (float*)d_out;

  const int npix = NN * HWPIX;  // 1,048,576 = 4096 * 256 exactly
  const size_t tbl_bytes = (size_t)PP * CC * sizeof(float);  // 64 MB

  if (ws_size >= tbl_bytes) {
    float* tbl = (float*)d_ws;
    transpose_tbl<<<(PP + 255) / 256, 256, 0, stream>>>(ptclds, tbl);
    composite<1><<<npix / 256, 256, 0, stream>>>(frag, zbuf, tbl, out);
  } else {
    composite<0><<<npix / 256, 256, 0, stream>>>(frag, zbuf, ptclds, out);
  }
}